// Round 12
// baseline (49.388 us; speedup 1.0000x reference)
//
#include <hip/hip_runtime.h>
#include <hip/hip_bf16.h>
#include <stdint.h>

// Conv2d, B=32, Cin=64, Cout=128, 3x3, stride 1, pad 1, H=W=56, fp32 in/out.
// Reference's mismatched flatten == standard conv with permuted weights:
// Weff for patch elem (c,di,dj) = K[f/192][(f%192)/64][f%64], f = c*9+di*3+dj.
// Reduction order g = di*192 + dj*64 + c => for fixed di, A's K-slice is
// CONTIGUOUS in padded-NHWC layout: byte (w*64+c)*2 within row (i+di).
// r12: r11 structure (fully-resident A+B-half in 119KB LDS, ZERO main-loop
// barriers, 896 blocks) with the swizzle CORRECTNESS FIX: r11's extra XOR of
// addr bits 2-3 broke 16B-granule consistency for global_load_lds/ds_read_b128
// (4B-aligned 16B chunks -> interleaved garbage). Swizzle must only touch
// bits >=4. Reverted to proven P(m)=(m&7)<<4 — which per-lane bank-group math
// shows is already uniform (8 lanes/4-bank-group) for b128 reads.

#define B_   32
#define CIN  64
#define COUT 128
#define H_   56
#define HP   58          // spatially padded
#define F_   576         // 9*64 reduction length

typedef __attribute__((ext_vector_type(8))) short bf16x8;
typedef __attribute__((ext_vector_type(4))) float f32x4;

#define XP_ELEMS (B_*HP*HP*CIN)          // 6,889,472
#define XP_SLACK 4096                    // 8KB: covers A-stage tail overread
#define XP_TOTAL (XP_ELEMS + XP_SLACK)
#define WG_ELEMS (COUT*F_)               // 73,728
#define WS_NEEDED ((size_t)(XP_TOTAL + WG_ELEMS) * 2)

#define NROW   (B_*HP)                   // 1856 x-row blocks
#define NWBLK  (WG_ELEMS/256)            // 288 weight blocks

// conv LDS (bytes): A tile [0, 45568); B-half frag-order [45568, 119296).
#define A_ALLOC 45568
#define B_BYTES (64*F_*2)                // 73,728
#define LDS_TOT (A_ALLOC + B_BYTES)      // 119,296

// A swizzle (16B-granule-safe involution): physical =
// (tot & ~127) | ((tot&127) ^ ((m&7)<<4)), m = tot>>7. Touches bits 4-6 only.
__device__ __forceinline__ int aswz(int tot) {
  return (tot & ~127) | ((tot & 127) ^ (((tot >> 7) & 7) << 4));
}

// ---------- fused prepass: x NCHW f32 -> padded NHWC bf16; K -> WgT[co][g] ----
__global__ __launch_bounds__(256) void prep_all(const float* __restrict__ x,
                                                const float* __restrict__ K,
                                                __hip_bfloat16* __restrict__ xpT,
                                                __hip_bfloat16* __restrict__ WgT) {
  const int id = blockIdx.x;
  const int t  = threadIdx.x;

  if (id > NROW) {                       // ---- weight permute blocks ----
    int n = (id - (NROW + 1))*256 + t;   // 288 full blocks
    int co = n / F_, g = n % F_;
    int di = g / 192, dj = (g % 192) / 64, c = g & 63;
    int f  = c*9 + di*3 + dj;
    int kh = f / 192, kw = (f % 192) / 64, cc = f & 63;
    WgT[n] = __float2bfloat16(K[(((size_t)kh*3 + kw)*CIN + cc)*COUT + co]);
    return;
  }
  if (id == NROW) {                      // ---- slack zero-fill ----
    bf16x8 z = (bf16x8)0;
    for (int idx = t; idx < XP_SLACK/8; idx += 256)
      ((bf16x8*)(xpT + XP_ELEMS))[idx] = z;
    return;
  }

  const int b = id / HP, h = id % HP;
  __hip_bfloat16* orow = xpT + (size_t)(b*HP + h) * HP * CIN;
  if (h == 0 || h == HP-1) {             // top/bottom pad rows
    bf16x8 z = (bf16x8)0;
    for (int idx = t; idx < HP*CIN/8; idx += 256) ((bf16x8*)orow)[idx] = z;
    return;
  }
  // slot-swizzled scratch: scr[c][slot][4], slot = (w4 + (c>>3)) & 15.
  __shared__ __align__(16) float scr[CIN*64];      // 16 KB
  const float* xrow = x + ((size_t)(b*CIN)*H_ + (h-1)) * H_;
  for (int idx = t; idx < CIN*14; idx += 256) {    // coalesced f32x4 reads
    int c = idx / 14, w4 = idx % 14;
    f32x4 v = *(const f32x4*)(xrow + (size_t)c*(H_*H_) + w4*4);
    *(f32x4*)&scr[c*64 + ((w4 + (c >> 3)) & 15)*4] = v;
  }
  __syncthreads();
  for (int idx = t; idx < HP*8; idx += 256) {      // bf16x8 writes
    int wp = idx >> 3, cg = (idx & 7) * 8;
    __align__(16) __hip_bfloat16 tmp[8];
    if (wp == 0 || wp == HP-1) {
#pragma unroll
      for (int k2 = 0; k2 < 8; ++k2) tmp[k2] = __float2bfloat16(0.f);
    } else {
      int w = wp - 1, sl = w >> 2, off = w & 3;
#pragma unroll
      for (int k2 = 0; k2 < 8; ++k2) {
        int c = cg + k2;
        tmp[k2] = __float2bfloat16(scr[c*64 + ((sl + (c >> 3)) & 15)*4 + off]);
      }
    }
    *(bf16x8*)(orow + (size_t)wp*CIN + cg) = *(const bf16x8*)tmp;
  }
}

// ---------- main: implicit GEMM, block = (b, 4 rows, co-half) -------------
// M=256 (224 real j's), N=64. 4 waves, wave = output row. Stage A+B once,
// ONE barrier, then 18 unrolled chunks of pure {8 ds_read_b128 + 16 MFMA}.
__global__ __launch_bounds__(256) void conv_mfma(
    const __hip_bfloat16* __restrict__ xpT,
    const __hip_bfloat16* __restrict__ WgT,
    float* __restrict__ out) {
  __shared__ __align__(16) char lds[LDS_TOT];
  const int t    = threadIdx.x;
  const int wave = t >> 6;               // wave w -> output row i0+w
  const int l    = t & 63;
  const int lr   = l & 15, lq = l >> 4;

  // bijective XCD swizzle: 896 = 8 * 112; consecutive swz share (bb,i0) in L2
  const int bid = blockIdx.x;
  const int swz = (bid & 7) * 112 + (bid >> 3);
  const int bb  = swz / 28;
  const int u   = swz % 28;
  const int i0  = (u >> 1) * 4;
  const int ch  = u & 1;                 // co-half

  f32x4 acc[4][4];
#pragma unroll
  for (int mi = 0; mi < 4; ++mi)
#pragma unroll
    for (int ni = 0; ni < 4; ++ni) acc[mi][ni] = (f32x4)0.f;

  const char* xb = (const char*)xpT + (size_t)(bb*HP + i0) * HP * CIN * 2;

  // ---- stage A once: 45,056 B (rows i0..i0+5 + tail-slack overread) ----
#pragma unroll
  for (int s = 0; s < 11; ++s) {
    int o = s*4096 + t*16;
    const char* src = xb + aswz(o);      // pre-swizzled source, linear dest
    __builtin_amdgcn_global_load_lds(
        (const __attribute__((address_space(1))) void*)src,
        (__attribute__((address_space(3))) void*)(lds + s*4096 + wave*1024),
        16, 0, 0);
  }
  // ---- stage B-half once: 72 KB in fragment order. Stage s = chunk s;
  // within: wave w stages frag ni=w: co = ch*64 + w*16 + (lane&15),
  // src = co*1152 + s*64 + (lane>>4)*16; dest wave-uniform, HW adds lane*16.
  {
    const char* wg = (const char*)WgT +
        (size_t)(ch*64 + wave*16 + lr)*1152 + lq*16;
#pragma unroll
    for (int s = 0; s < 18; ++s) {
      __builtin_amdgcn_global_load_lds(
          (const __attribute__((address_space(1))) void*)(wg + s*64),
          (__attribute__((address_space(3))) void*)
              (lds + A_ALLOC + s*4096 + wave*1024),
          16, 0, 0);
    }
  }
  __syncthreads();                       // the ONLY barrier

  // ---- main loop: 18 chunks of k=32, no staging, no barriers ----
#pragma unroll
  for (int hc = 0; hc < 18; ++hc) {
    const int kg  = hc*32;
    const int di  = kg / 192;
    const int rem = kg - di*192;         // dj*64 + c0 within di-slab
    bf16x8 a[4], bq[4];
#pragma unroll
    for (int mi = 0; mi < 4; ++mi) {
      int tot = ((wave + di)*HP + mi*16 + lr)*128 + rem*2 + lq*16;
      a[mi] = *(const bf16x8*)(lds + aswz(tot));
    }
#pragma unroll
    for (int ni = 0; ni < 4; ++ni)       // frag-order: linear, conflict-free
      bq[ni] = *(const bf16x8*)(lds + A_ALLOC + hc*4096 + ni*1024 + l*16);
    __builtin_amdgcn_s_setprio(1);
#pragma unroll
    for (int mi = 0; mi < 4; ++mi)
#pragma unroll
      for (int ni = 0; ni < 4; ++ni)
        acc[mi][ni] = __builtin_amdgcn_mfma_f32_16x16x32_bf16(
            a[mi], bq[ni], acc[mi][ni], 0, 0, 0);
    __builtin_amdgcn_s_setprio(0);
  }

  // epilogue: C/D layout col=lane&15 -> co, row=(lane>>4)*4+reg -> j
  const int i = i0 + wave;
#pragma unroll
  for (int mi = 0; mi < 4; ++mi) {
    int j0 = mi*16 + lq*4;
    if (j0 < H_) {
#pragma unroll
      for (int ni = 0; ni < 4; ++ni) {
        int co = ch*64 + ni*16 + lr;
        float* dst = out + (((size_t)(bb*COUT + co))*H_ + i)*H_ + j0;
        *(f32x4*)dst = acc[mi][ni];
      }
    }
  }
}

// ---------- fallback (workspace too small): naive fp32 direct ----------
__global__ __launch_bounds__(256) void conv_naive(const float* __restrict__ x,
                                                  const float* __restrict__ K,
                                                  float* __restrict__ out) {
  int idx = blockIdx.x*256 + threadIdx.x;
  const int total = B_*COUT*H_*H_;
  if (idx >= total) return;
  int j = idx % H_, i = (idx / H_) % H_, co = (idx / (H_*H_)) % COUT, b = idx / (H_*H_*COUT);
  float s = 0.f;
  for (int c = 0; c < CIN; ++c)
    for (int di = 0; di < 3; ++di) {
      int ii = i + di - 1;
      if (ii < 0 || ii >= H_) continue;
      for (int dj = 0; dj < 3; ++dj) {
        int jj = j + dj - 1;
        if (jj < 0 || jj >= H_) continue;
        int f = c*9 + di*3 + dj;
        int kh = f / 192, kw = (f % 192) / 64, cc = f & 63;
        s += x[(((size_t)b*CIN + c)*H_ + ii)*H_ + jj] *
             K[(((size_t)kh*3 + kw)*CIN + cc)*COUT + co];
      }
    }
  out[idx] = s;
}

extern "C" void kernel_launch(void* const* d_in, const int* in_sizes, int n_in,
                              void* d_out, int out_size, void* d_ws, size_t ws_size,
                              hipStream_t stream) {
  const float* x = (const float*)d_in[0];
  const float* K = (const float*)d_in[1];
  float* out = (float*)d_out;
  if (ws_size >= WS_NEEDED) {
    __hip_bfloat16* xpT = (__hip_bfloat16*)d_ws;
    __hip_bfloat16* WgT = xpT + XP_TOTAL;
    prep_all<<<NROW + 1 + NWBLK, 256, 0, stream>>>(x, K, xpT, WgT);
    conv_mfma<<<B_*28, 256, 0, stream>>>(xpT, WgT, out);
  } else {
    conv_naive<<<(B_*COUT*H_*H_ + 255)/256, 256, 0, stream>>>(x, K, out);
  }
}

// Round 13
// 38.592 us; speedup vs baseline: 1.2798x; 1.2798x over previous
//
#include <hip/hip_runtime.h>
#include <hip/hip_bf16.h>
#include <stdint.h>

// Conv2d, B=32, Cin=64, Cout=128, 3x3, stride 1, pad 1, H=W=56, fp32 in/out.
// Reference's mismatched flatten == standard conv with permuted weights:
// Weff for patch elem (c,di,dj) = K[f/192][(f%192)/64][f%64], f = c*9+di*3+dj.
// Reduction order g = di*192 + dj*64 + c => for fixed di, A's K-slice is
// CONTIGUOUS in padded-NHWC layout: byte (w*64+c)*2 within row (i+di);
// the dj shift folds into +dj*128 bytes (one position stride).
// r13: fully-resident A+B-half, ZERO main-loop barriers, 8 waves/block
// (512 thr, 2 waves/SIMD free-running). B staged COALESCED (r12's regression
// was its 16-line-per-instr gather staging) with both-sides XOR swizzle
// within each 1152B weight row; A staged coalesced with row-XOR swizzle.
// LDS 147,968B; grid 448 (1.75 rounds/CU).

#define B_   32
#define CIN  64
#define COUT 128
#define H_   56
#define HP   58          // spatially padded
#define F_   576         // 9*64 reduction length

typedef __attribute__((ext_vector_type(8))) short bf16x8;
typedef __attribute__((ext_vector_type(4))) float f32x4;

#define XP_ELEMS (B_*HP*HP*CIN)          // 6,889,472
#define XP_SLACK 4096
#define XP_TOTAL (XP_ELEMS + XP_SLACK)
#define WG_ELEMS (COUT*F_)               // 73,728
#define WS_NEEDED ((size_t)(XP_TOTAL + WG_ELEMS) * 2)

#define NROW   (B_*HP)                   // 1856 x-row blocks
#define NWBLK  (WG_ELEMS/256)            // 288 weight blocks

// conv LDS: A tile [0, 74240) = 580 rows x 128B; B-half [74240, 147968).
#define A_ALLOC 74240
#define LDS_TOT (A_ALLOC + 64*F_*2)      // 147,968 <= 160KB

// A swizzle (16B-granule involution, bits 4-6): quad-uniform for b128 reads.
__device__ __forceinline__ int aswz(int tot) {
  return (tot & ~127) | ((tot & 127) ^ (((tot >> 7) & 7) << 4));
}

// ---------- fused prepass: x NCHW f32 -> padded NHWC bf16; K -> WgT[co][g] ----
__global__ __launch_bounds__(256) void prep_all(const float* __restrict__ x,
                                                const float* __restrict__ K,
                                                __hip_bfloat16* __restrict__ xpT,
                                                __hip_bfloat16* __restrict__ WgT) {
  const int id = blockIdx.x;
  const int t  = threadIdx.x;

  if (id > NROW) {                       // ---- weight permute blocks ----
    int n = (id - (NROW + 1))*256 + t;   // 288 full blocks
    int co = n / F_, g = n % F_;
    int di = g / 192, dj = (g % 192) / 64, c = g & 63;
    int f  = c*9 + di*3 + dj;
    int kh = f / 192, kw = (f % 192) / 64, cc = f & 63;
    WgT[n] = __float2bfloat16(K[(((size_t)kh*3 + kw)*CIN + cc)*COUT + co]);
    return;
  }
  if (id == NROW) {                      // ---- slack zero-fill ----
    bf16x8 z = (bf16x8)0;
    for (int idx = t; idx < XP_SLACK/8; idx += 256)
      ((bf16x8*)(xpT + XP_ELEMS))[idx] = z;
    return;
  }

  const int b = id / HP, h = id % HP;
  __hip_bfloat16* orow = xpT + (size_t)(b*HP + h) * HP * CIN;
  if (h == 0 || h == HP-1) {             // top/bottom pad rows
    bf16x8 z = (bf16x8)0;
    for (int idx = t; idx < HP*CIN/8; idx += 256) ((bf16x8*)orow)[idx] = z;
    return;
  }
  // slot-swizzled scratch: scr[c][slot][4], slot = (w4 + (c>>3)) & 15.
  __shared__ __align__(16) float scr[CIN*64];      // 16 KB
  const float* xrow = x + ((size_t)(b*CIN)*H_ + (h-1)) * H_;
  for (int idx = t; idx < CIN*14; idx += 256) {    // coalesced f32x4 reads
    int c = idx / 14, w4 = idx % 14;
    f32x4 v = *(const f32x4*)(xrow + (size_t)c*(H_*H_) + w4*4);
    *(f32x4*)&scr[c*64 + ((w4 + (c >> 3)) & 15)*4] = v;
  }
  __syncthreads();
  for (int idx = t; idx < HP*8; idx += 256) {      // bf16x8 writes
    int wp = idx >> 3, cg = (idx & 7) * 8;
    __align__(16) __hip_bfloat16 tmp[8];
    if (wp == 0 || wp == HP-1) {
#pragma unroll
      for (int k2 = 0; k2 < 8; ++k2) tmp[k2] = __float2bfloat16(0.f);
    } else {
      int w = wp - 1, sl = w >> 2, off = w & 3;
#pragma unroll
      for (int k2 = 0; k2 < 8; ++k2) {
        int c = cg + k2;
        tmp[k2] = __float2bfloat16(scr[c*64 + ((sl + (c >> 3)) & 15)*4 + off]);
      }
    }
    *(bf16x8*)(orow + (size_t)wp*CIN + cg) = *(const bf16x8*)tmp;
  }
}

// ---------- main: block = (b, 8 rows, co-half), 512 threads / 8 waves ------
// wave = output row. Stage A (74,240B) + B-half (73,728B) once, coalesced;
// ONE barrier; 18 unrolled chunks of pure ds_read+MFMA, no sync.
__global__ __launch_bounds__(512, 2) void conv_mfma(
    const __hip_bfloat16* __restrict__ xpT,
    const __hip_bfloat16* __restrict__ WgT,
    float* __restrict__ out) {
  __shared__ __align__(16) char lds[LDS_TOT];
  const int t    = threadIdx.x;
  const int wave = t >> 6;               // wave w -> output row i0+w
  const int l    = t & 63;
  const int lr   = l & 15, lq = l >> 4;

  // bijective XCD swizzle: 448 = 8 * 56
  const int bid = blockIdx.x;
  const int swz = (bid & 7) * 56 + (bid >> 3);
  const int bb  = swz / 14;
  const int u   = swz % 14;              // 7 i-tiles x 2 co-halves
  const int i0  = (u >> 1) * 8;
  const int ch  = u & 1;

  f32x4 acc[4][4];
#pragma unroll
  for (int mi = 0; mi < 4; ++mi)
#pragma unroll
    for (int ni = 0; ni < 4; ++ni) acc[mi][ni] = (f32x4)0.f;

  const char* xb = (const char*)xpT + (size_t)(bb*HP + i0) * HP * CIN * 2;
  const char* wh = (const char*)WgT + (size_t)(ch*64)*1152;

  // ---- stage A: 74,240B = 9 x 8KB + 512B tail (coalesced, swizzled src) ----
#pragma unroll
  for (int s = 0; s < 9; ++s) {
    int o = s*8192 + t*16;
    __builtin_amdgcn_global_load_lds(
        (const __attribute__((address_space(1))) void*)(xb + aswz(o)),
        (__attribute__((address_space(3))) void*)(lds + s*8192 + wave*1024),
        16, 0, 0);
  }
  if (t < 32) {                          // tail rows 576..579 (512B), wave 0
    int o = 73728 + t*16;
    __builtin_amdgcn_global_load_lds(
        (const __attribute__((address_space(1))) void*)(xb + aswz(o)),
        (__attribute__((address_space(3))) void*)(lds + 73728),
        16, 0, 0);
  }
  // ---- stage B-half: 73,728B = 9 x 8KB coalesced; source pre-swizzled
  // within each 1152B co-row: src_off(o) = o - rb + (rb ^ ((co&7)<<4)).
#pragma unroll
  for (int s = 0; s < 9; ++s) {
    int o  = s*8192 + t*16;
    int co = o / 1152;                   // magic-mul
    int rb = o - co*1152;
    __builtin_amdgcn_global_load_lds(
        (const __attribute__((address_space(1))) void*)
            (wh + co*1152 + (rb ^ ((co & 7) << 4))),
        (__attribute__((address_space(3))) void*)
            (lds + A_ALLOC + s*8192 + wave*1024),
        16, 0, 0);
  }
  __syncthreads();                       // the ONLY barrier

  // ---- main loop: 18 chunks of k=32, pure LDS+MFMA, free-running waves ----
#pragma unroll
  for (int hc = 0; hc < 18; ++hc) {
    const int kg  = hc*32;
    const int di  = kg / 192;
    const int rem = kg - di*192;         // dj*64 + c0 (elems); *2 folds dj
    bf16x8 a[4], bq[4];
#pragma unroll
    for (int mi = 0; mi < 4; ++mi) {
      int tot = ((wave + di)*HP + mi*16 + lr)*128 + rem*2 + lq*16;
      a[mi] = *(const bf16x8*)(lds + aswz(tot));
    }
    const int kb = hc*64 + lq*16;        // byte offset within co-row
#pragma unroll
    for (int ni = 0; ni < 4; ++ni) {
      int co = ni*16 + lr;
      bq[ni] = *(const bf16x8*)(lds + A_ALLOC + co*1152 + (kb ^ ((co & 7) << 4)));
    }
    __builtin_amdgcn_s_setprio(1);
#pragma unroll
    for (int mi = 0; mi < 4; ++mi)
#pragma unroll
      for (int ni = 0; ni < 4; ++ni)
        acc[mi][ni] = __builtin_amdgcn_mfma_f32_16x16x32_bf16(
            a[mi], bq[ni], acc[mi][ni], 0, 0, 0);
    __builtin_amdgcn_s_setprio(0);
  }

  // epilogue: C/D layout col=lane&15 -> co, row=(lane>>4)*4+reg -> j
  const int i = i0 + wave;
#pragma unroll
  for (int mi = 0; mi < 4; ++mi) {
    int j0 = mi*16 + lq*4;
    if (j0 < H_) {
#pragma unroll
      for (int ni = 0; ni < 4; ++ni) {
        int co = ch*64 + ni*16 + lr;
        float* dst = out + (((size_t)(bb*COUT + co))*H_ + i)*H_ + j0;
        *(f32x4*)dst = acc[mi][ni];
      }
    }
  }
}

// ---------- fallback (workspace too small): naive fp32 direct ----------
__global__ __launch_bounds__(256) void conv_naive(const float* __restrict__ x,
                                                  const float* __restrict__ K,
                                                  float* __restrict__ out) {
  int idx = blockIdx.x*256 + threadIdx.x;
  const int total = B_*COUT*H_*H_;
  if (idx >= total) return;
  int j = idx % H_, i = (idx / H_) % H_, co = (idx / (H_*H_)) % COUT, b = idx / (H_*H_*COUT);
  float s = 0.f;
  for (int c = 0; c < CIN; ++c)
    for (int di = 0; di < 3; ++di) {
      int ii = i + di - 1;
      if (ii < 0 || ii >= H_) continue;
      for (int dj = 0; dj < 3; ++dj) {
        int jj = j + dj - 1;
        if (jj < 0 || jj >= H_) continue;
        int f = c*9 + di*3 + dj;
        int kh = f / 192, kw = (f % 192) / 64, cc = f & 63;
        s += x[(((size_t)b*CIN + c)*H_ + ii)*H_ + jj] *
             K[(((size_t)kh*3 + kw)*CIN + cc)*COUT + co];
      }
    }
  out[idx] = s;
}

extern "C" void kernel_launch(void* const* d_in, const int* in_sizes, int n_in,
                              void* d_out, int out_size, void* d_ws, size_t ws_size,
                              hipStream_t stream) {
  const float* x = (const float*)d_in[0];
  const float* K = (const float*)d_in[1];
  float* out = (float*)d_out;
  if (ws_size >= WS_NEEDED) {
    __hip_bfloat16* xpT = (__hip_bfloat16*)d_ws;
    __hip_bfloat16* WgT = xpT + XP_TOTAL;
    prep_all<<<NROW + 1 + NWBLK, 256, 0, stream>>>(x, K, xpT, WgT);
    conv_mfma<<<B_*14, 512, 0, stream>>>(xpT, WgT, out);
  } else {
    conv_naive<<<(B_*COUT*H_*H_ + 255)/256, 256, 0, stream>>>(x, K, out);
  }
}